// Round 8
// baseline (1129.259 us; speedup 1.0000x reference)
//
#include <hip/hip_runtime.h>

#define CDIV(a, b) (((a) + (b) - 1) / (b))

typedef float __attribute__((ext_vector_type(2))) f32x2;
typedef float __attribute__((ext_vector_type(4))) f32x4;

// Packed fp32 FMA: d = a*b + d (per 32-bit half). MI355X full fp32 rate
// (157 TF) is only reachable via VOP3P packed math; scalar v_fmac = half.
__device__ __forceinline__ void pk_fma(f32x2& d, f32x2 a, f32x2 b) {
    asm("v_pk_fma_f32 %0, %1, %2, %0" : "+v"(d) : "v"(a), "v"(b));
}

// Native fp32 atomic add for GLOBAL memory (outlier path only; ~never taken).
__device__ __forceinline__ void fadd_native(float* p, float v) {
    unsafeAtomicAdd(p, v);
}

// ---------------------------------------------------------------------------
// Weight transpose: w[co][ci][k] -> wT[ci][k][co] so the conv can read
// weights at block-uniform, 16B-aligned addresses (scalar/SMEM path or
// L1-broadcast) instead of 36 ds_read_b128 per ci (the R7 DS-pipe bottleneck).
// ---------------------------------------------------------------------------
__global__ void wtrans_kernel(const float* __restrict__ w,
                              float* __restrict__ wT, int Co, int Ci) {
    const int idx = blockIdx.x * blockDim.x + threadIdx.x;
    if (idx >= Co * Ci * 9) return;
    const int co = idx / (Ci * 9);
    const int rem = idx - co * Ci * 9;
    const int ci = rem / 9, k = rem - ci * 9;
    wT[((size_t)ci * 9 + k) * Co + co] = w[idx];
}

// ---------------------------------------------------------------------------
// Conv 3x3 pad1 stride{1,2} v3.
// 256 threads as 16x16; thread owns PX x PY pixels STRIDED by 16 (conflict-
// free taps, coalesced stores) for 16 output channels (8 f32x2 accumulators
// per pixel). Input plane staged in LDS (padded odd stride), register
// prefetch double-buffer. Weights read from transposed global (uniform).
// PART=1: write raw partial sums to out[((spl*16+b)*Co+co)*HW + ...]
// (Ci-split across blockIdx.y = spl*nCog+cog) — reduced by reduce_prelu.
// ---------------------------------------------------------------------------
template <int STRIDE, int TW, int TH, int PART>
__global__ __launch_bounds__(256)
void conv3x3_v3(const float* __restrict__ in, const float* __restrict__ wT,
                const float* __restrict__ bias, const float* __restrict__ alpha,
                float* __restrict__ out, int Ci, int CL, int Hi, int Wi,
                int Co, int Ho, int Wo, int nTX, int nCog) {
    constexpr int PX = TW / 16, PY = TH / 16;
    constexpr int ISX = TW * STRIDE + 2, ISY = TH * STRIDE + 2;
    constexpr int PAD = ISX + 1;          // odd -> bank spread
    constexpr int NEL = ISY * ISX;
    constexpr int NST = (NEL + 255) / 256;
    __shared__ float s_in[ISY * PAD];

    const int b   = blockIdx.z;
    const int cog = blockIdx.y % nCog;
    const int spl = blockIdx.y / nCog;
    const int co0 = cog * 16;
    const int ci0 = spl * CL;
    const int tX  = (blockIdx.x % nTX) * TW;
    const int tY  = (blockIdx.x / nTX) * TH;
    const int t   = threadIdx.x;
    const int tcx = t & 15, tcy = t >> 4;
    const int HiWi = Hi * Wi;

    int poff[NST], pdst[NST];
    bool pval[NST];
    const int ix0 = tX * STRIDE - 1, iy0 = tY * STRIDE - 1;
#pragma unroll
    for (int s = 0; s < NST; ++s) {
        const int i = t + s * 256;
        poff[s] = 0; pdst[s] = 0; pval[s] = false;
        if (i < NEL) {
            const int r = i / ISX, c = i - r * ISX;
            const int gy = iy0 + r, gx = ix0 + c;
            pval[s] = (gy >= 0) && (gy < Hi) && (gx >= 0) && (gx < Wi);
            poff[s] = pval[s] ? gy * Wi + gx : 0;
            pdst[s] = r * PAD + c;
        }
    }

    f32x2 acc[8][PY][PX];
#pragma unroll
    for (int p = 0; p < 8; ++p)
#pragma unroll
        for (int py = 0; py < PY; ++py)
#pragma unroll
            for (int m = 0; m < PX; ++m) acc[p][py][m] = (f32x2){0.f, 0.f};

    const float* inb = in + ((size_t)b * Ci + ci0) * HiWi;
    float rs[NST];
#pragma unroll
    for (int s = 0; s < NST; ++s) rs[s] = pval[s] ? inb[poff[s]] : 0.f;

    for (int cc = 0; cc < CL; ++cc) {
        __syncthreads();
#pragma unroll
        for (int s = 0; s < NST; ++s)
            if (t + s * 256 < NEL) s_in[pdst[s]] = rs[s];
        if (cc + 1 < CL) {
            const float* nb = inb + (size_t)(cc + 1) * HiWi;
#pragma unroll
            for (int s = 0; s < NST; ++s) rs[s] = pval[s] ? nb[poff[s]] : 0.f;
        }
        __syncthreads();

        const float* wrow = wT + (size_t)(ci0 + cc) * 9 * Co + co0;
#pragma unroll
        for (int ky = 0; ky < 3; ++ky)
#pragma unroll
            for (int kx = 0; kx < 3; ++kx) {
                f32x2 t2[PY][PX];
#pragma unroll
                for (int py = 0; py < PY; ++py)
#pragma unroll
                    for (int m = 0; m < PX; ++m) {
                        const float tv =
                            s_in[((tcy + 16 * py) * STRIDE + ky) * PAD +
                                 (tcx + 16 * m) * STRIDE + kx];
                        t2[py][m] = (f32x2){tv, tv};
                    }
                const float* wk = wrow + (ky * 3 + kx) * Co;
#pragma unroll
                for (int kq = 0; kq < 4; ++kq) {
                    const f32x4 w4 =
                        *reinterpret_cast<const f32x4*>(wk + 4 * kq);
                    const f32x2 wlo = {w4[0], w4[1]};
                    const f32x2 whi = {w4[2], w4[3]};
#pragma unroll
                    for (int py = 0; py < PY; ++py)
#pragma unroll
                        for (int m = 0; m < PX; ++m) {
                            pk_fma(acc[2 * kq][py][m], t2[py][m], wlo);
                            pk_fma(acc[2 * kq + 1][py][m], t2[py][m], whi);
                        }
                }
            }
    }

    const size_t HoWo = (size_t)Ho * Wo;
#pragma unroll
    for (int p = 0; p < 8; ++p) {
        const int cbase = co0 + 4 * (p >> 1) + 2 * (p & 1);
#pragma unroll
        for (int h = 0; h < 2; ++h) {
            const int co = cbase + h;
            float bv = 0.f, av = 0.f;
            if constexpr (!PART) { bv = bias[co]; av = alpha[co]; }
#pragma unroll
            for (int py = 0; py < PY; ++py) {
                const int oy = tY + tcy + 16 * py;
#pragma unroll
                for (int m = 0; m < PX; ++m) {
                    const int ox = tX + tcx + 16 * m;
                    float v = acc[p][py][m][h];
                    if constexpr (PART) {
                        out[((size_t)((spl << 4) + b) * Co + co) * HoWo +
                            (size_t)oy * Wo + ox] = v;
                    } else {
                        v += bv;
                        v = v >= 0.f ? v : av * v;
                        out[((size_t)b * Co + co) * HoWo +
                            (size_t)oy * Wo + ox] = v;
                    }
                }
            }
        }
    }
}

// ---------------------------------------------------------------------------
// Sum Ci-split partials + bias + PReLU (float4 vectorized).
// part layout: [spl][b][co][hw], per-split stride N = 4*N4 elements.
// ---------------------------------------------------------------------------
__global__ void reduce_prelu_kernel(const float* __restrict__ part,
                                    const float* __restrict__ bias,
                                    const float* __restrict__ alpha,
                                    float* __restrict__ out,
                                    int nspl, int N4, int Co, int HW) {
    const int i4 = blockIdx.x * blockDim.x + threadIdx.x;
    if (i4 >= N4) return;
    const size_t idx = (size_t)i4 * 4;
    const size_t N = (size_t)N4 * 4;
    f32x4 s = *reinterpret_cast<const f32x4*>(part + idx);
    for (int sp = 1; sp < nspl; ++sp) {
        const f32x4 q =
            *reinterpret_cast<const f32x4*>(part + (size_t)sp * N + idx);
        s[0] += q[0]; s[1] += q[1]; s[2] += q[2]; s[3] += q[3];
    }
    const int co = (int)((idx / HW) % Co);
    const float bv = bias[co], av = alpha[co];
    float4 o;
    float v0 = s[0] + bv; o.x = v0 >= 0.f ? v0 : av * v0;
    float v1 = s[1] + bv; o.y = v1 >= 0.f ? v1 : av * v1;
    float v2 = s[2] + bv; o.z = v2 >= 0.f ? v2 : av * v2;
    float v3 = s[3] + bv; o.w = v3 >= 0.f ? v3 : av * v3;
    *reinterpret_cast<float4*>(out + idx) = o;
}

// ---------------------------------------------------------------------------
// flow halving: 2x2 mean * 0.5 == sum * 0.125
// ---------------------------------------------------------------------------
__global__ void halve_flow_kernel(const float* __restrict__ in,
                                  float* __restrict__ out,
                                  int BC, int Ho, int Wo, int Hi, int Wi) {
    const int idx = blockIdx.x * blockDim.x + threadIdx.x;
    const int total = BC * Ho * Wo;
    if (idx >= total) return;
    const int wo = idx % Wo;
    int t = idx / Wo;
    const int ho = t % Ho;
    const int bc = t / Ho;
    const float* p = in + ((size_t)bc * Hi + 2 * ho) * Wi + 2 * wo;
    out[idx] = (p[0] + p[1] + p[Wi] + p[Wi + 1]) * 0.125f;
}

// ---------------------------------------------------------------------------
// Outlier splat pre-pass (atomics; ~never taken). thr == (float)(K-1).
// ---------------------------------------------------------------------------
__global__ void splat_outlier_kernel(const float* __restrict__ feat,
                                     const float* __restrict__ flow,
                                     float* __restrict__ num,
                                     float* __restrict__ cnt,
                                     int B, int C, int H, int W, float thr) {
    const int HW = H * W;
    const int idx = blockIdx.x * blockDim.x + threadIdx.x;
    if (idx >= B * HW) return;
    const int b = idx / HW, px = idx - b * HW;
    const int y = px / W, x = px - y * W;
    const float dx = flow[(size_t)b * 2 * HW + px];
    const float dy = flow[(size_t)b * 2 * HW + HW + px];
    if (fabsf(dx) <= thr && fabsf(dy) <= thr) return;
    const float fx = dx + (float)x, fy = dy + (float)y;
    const float x0f = floorf(fx), y0f = floorf(fy);
    const int x0 = (int)x0f, y0 = (int)y0f;
    const float ax = fx - x0f, ay = fy - y0f;
    const float w[4] = {(1.f - ax) * (1.f - ay), ax * (1.f - ay),
                        (1.f - ax) * ay,         ax * ay};
    const int cx[4] = {x0, x0 + 1, x0, x0 + 1};
    const int cy[4] = {y0, y0, y0 + 1, y0 + 1};
    float* cb = cnt + (size_t)b * HW;
    for (int k = 0; k < 4; ++k) {
        if (cx[k] < 0 || cx[k] >= W || cy[k] < 0 || cy[k] >= H) continue;
        if (w[k] == 0.f) continue;
        const size_t d = (size_t)cy[k] * W + cx[k];
        fadd_native(cb + d, w[k]);
        for (int c = 0; c < C; ++c)
            fadd_native(num + ((size_t)b * C + c) * HW + d,
                        feat[((size_t)b * C + c) * HW + px] * w[k]);
    }
}

// ---------------------------------------------------------------------------
// GATHER splat v2 (unchanged from R7): zero atomics, channel-streamed LDS.
// ---------------------------------------------------------------------------
template <int TS, int K, int NCH, int HCAP>
__global__ __launch_bounds__(256)
void splat_gather2_kernel(const float* __restrict__ feat,
                          const float* __restrict__ flow,
                          const float* __restrict__ cnt_ov,
                          float* __restrict__ out,
                          int C, int H, int W, int nTX) {
    constexpr int WS   = TS + 2 * K;
    constexpr int SSTR = WS + 1;
    constexpr int RUN  = TS * TS / 256;
    constexpr int TPR  = TS / RUN;
    constexpr int NSF  = (WS * WS + 255) / 256;
    constexpr float THR = (float)(K - 1);
    __shared__ __align__(8) float s_xy[2 * WS * SSTR];
    __shared__ float s_feat[WS * SSTR];
    __shared__ unsigned short s_hit[256 * HCAP];

    const int b   = blockIdx.z;
    const int c0  = blockIdx.y * NCH;
    const int tx0 = (blockIdx.x % nTX) * TS;
    const int ty0 = (blockIdx.x / nTX) * TS;
    const int t   = threadIdx.x;
    const int HW  = H * W;
    const float* flx = flow + (size_t)b * 2 * HW;
    const float* fly = flx + HW;
    const float* fb  = feat + ((size_t)b * C + c0) * HW;

    int  foff[NSF], sdst[NSF];
    bool fval[NSF];
#pragma unroll
    for (int s = 0; s < NSF; ++s) {
        const int i = t + s * 256;
        foff[s] = 0; sdst[s] = 0; fval[s] = false;
        if (i < WS * WS) {
            const int wsy = i / WS, wsx = i - wsy * WS;
            const int gy = ty0 - K + wsy, gx = tx0 - K + wsx;
            const int off = wsy * SSTR + wsx;
            sdst[s] = off;
            float fxr = 1e9f, fyr = 1e9f;
            if (gy >= 0 && gy < H && gx >= 0 && gx < W) {
                fval[s] = true;
                foff[s] = gy * W + gx;
                const float dxf = flx[foff[s]];
                const float dyf = fly[foff[s]];
                if (fabsf(dxf) <= THR && fabsf(dyf) <= THR) {
                    fxr = dxf + (float)(gx - tx0);
                    fyr = dyf + (float)(gy - ty0);
                }
            }
            *reinterpret_cast<f32x2*>(&s_xy[2 * off]) = (f32x2){fxr, fyr};
        }
    }
    __syncthreads();

    const int r  = t / TPR;
    const int x0 = (t % TPR) * RUN;

    int n = 0;
    unsigned short* hl = s_hit + t * HCAP;
#pragma unroll
    for (int dy = 0; dy <= 2 * K; ++dy) {
        const int wsy = r + dy;
        const int base = wsy * SSTR + x0;
#pragma unroll
        for (int dxx = 0; dxx < RUN + 2 * K; ++dxx) {
            const f32x2 xy =
                *reinterpret_cast<const f32x2*>(&s_xy[2 * (base + dxx)]);
            const float ty = xy[1] - (float)r;
            const float ux = xy[0] - (float)x0;
            if (ty > -1.f && ty < 1.f && ux > -1.f && ux < (float)RUN &&
                n < HCAP) {
                hl[n] = (unsigned short)((wsy << 6) | (x0 + dxx));
                ++n;
            }
        }
    }

    const int gyd = ty0 + r;
    const size_t rowoff = (size_t)gyd * W + (tx0 + x0);
    float cv_ov[RUN];
#pragma unroll
    for (int m = 0; m < RUN; ++m)
        cv_ov[m] = cnt_ov[(size_t)b * HW + rowoff + m];

    float rs[NSF];
#pragma unroll
    for (int s = 0; s < NSF; ++s) rs[s] = fval[s] ? fb[foff[s]] : 0.f;

    float inv[RUN];
#pragma unroll
    for (int ch = 0; ch < NCH; ++ch) {
        __syncthreads();
#pragma unroll
        for (int s = 0; s < NSF; ++s)
            if (t + s * 256 < WS * WS) s_feat[sdst[s]] = rs[s];
        if (ch + 1 < NCH) {
            const float* nfb = fb + (size_t)(ch + 1) * HW;
#pragma unroll
            for (int s = 0; s < NSF; ++s) rs[s] = fval[s] ? nfb[foff[s]] : 0.f;
        }
        __syncthreads();

        float a[RUN];
        float cw[RUN];
#pragma unroll
        for (int m = 0; m < RUN; ++m) { a[m] = 0.f; cw[m] = 0.f; }
        for (int k = 0; k < n; ++k) {
            const int idx = hl[k];
            const int off = (idx >> 6) * SSTR + (idx & 63);
            const f32x2 xy = *reinterpret_cast<const f32x2*>(&s_xy[2 * off]);
            const float f = s_feat[off];
            const float wy = 1.f - fabsf(xy[1] - (float)r);
            const float ux = xy[0] - (float)x0;
#pragma unroll
            for (int m = 0; m < RUN; ++m) {
                const float wm = fmaxf(0.f, 1.f - fabsf(ux - (float)m)) * wy;
                a[m] = fmaf(wm, f, a[m]);
                if (ch == 0) cw[m] += wm;
            }
        }
        if (ch == 0) {
#pragma unroll
            for (int m = 0; m < RUN; ++m) {
                const float cv = cw[m] + cv_ov[m];
                inv[m] = 1.f / ((cv == 0.f) ? 1.f : cv);
            }
        }

        const size_t go = ((size_t)b * C + (c0 + ch)) * HW + rowoff;
        if constexpr (RUN == 4) {
            float vv[4];
#pragma unroll
            for (int m = 0; m < 4; ++m) {
                float x = a[m];
                if (cv_ov[m] != 0.f) x += out[go + m];
                vv[m] = x * inv[m];
            }
            float4 v4 = {vv[0], vv[1], vv[2], vv[3]};
            *reinterpret_cast<float4*>(out + go) = v4;
        } else {
            float x = a[0];
            if (cv_ov[0] != 0.f) x += out[go];
            out[go] = x * inv[0];
        }
    }
}

extern "C" void kernel_launch(void* const* d_in, const int* in_sizes, int n_in,
                              void* d_out, int out_size, void* d_ws, size_t ws_size,
                              hipStream_t stream) {
    (void)in_sizes; (void)n_in; (void)ws_size;

    const float* img  = (const float*)d_in[0];
    const float* flow = (const float*)d_in[1];
    const float* P[4][6];
    for (int i = 0; i < 4; ++i)
        for (int j = 0; j < 6; ++j)
            P[i][j] = (const float*)d_in[2 + 6 * i + j];

    const int Bn = 16;
    float* ws  = (float*)d_ws;
    float* W0  = ws;                    // 16,777,216  feat1 (persists to end)
    float* A   = ws + 16777216;         //  8,388,608  conv-a scratch
    float* Bf  = ws + 25165824;         //  8,388,608  conv-b out (feat2/3/4)
    float* fl1 = ws + 33554432;         //  2,097,152
    float* fl2 = ws + 35651584;         //    524,288
    float* fl3 = ws + 36175872;         //    131,072
    float* fl4 = ws + 36306944;         //     32,768
    float* cnt = ws + 36339712;         //  1,048,576
    float* wTb = ws + 37388288;         //    147,456
    float* out = (float*)d_out;

    float* p1 = out;                                   // 16,777,216 floats
    float* p2 = p1 + (size_t)Bn * 16 * 256 * 256;
    float* p3 = p2 + (size_t)Bn * 32 * 128 * 128;
    float* p4 = p3 + (size_t)Bn * 64 * 64 * 64;

    hipMemsetAsync(d_out, 0, (size_t)out_size * sizeof(float), stream);

    auto halve = [&](const float* in, float* o, int Hi, int Wi) {
        const int Ho = Hi / 2, Wo = Wi / 2;
        const int total = Bn * 2 * Ho * Wo;
        hipLaunchKernelGGL(halve_flow_kernel, dim3(CDIV(total, 256)), dim3(256),
                           0, stream, in, o, Bn * 2, Ho, Wo, Hi, Wi);
    };

// Ci-split partials live in p1 (free until the final splat1); max exactly
// 16,777,216 floats (CSPL*Bn*Co*HW) for L2b/L3b/L4b.
#define DO_CONV(S, TWv, THv, CSPLv, inp, Wp, Bp, Ap, dst, Ci_, Hi_, Wi_, Co_)  \
    do {                                                                       \
        const int Ho_ = (Hi_) / (S), Wo_ = (Wi_) / (S);                        \
        const int nTX_ = Wo_ / (TWv), nTY_ = Ho_ / (THv);                      \
        const int nCog_ = (Co_) / 16;                                          \
        hipLaunchKernelGGL(wtrans_kernel, dim3(CDIV((Co_) * (Ci_) * 9, 256)),  \
                           dim3(256), 0, stream, Wp, wTb, Co_, Ci_);           \
        if ((CSPLv) == 1) {                                                    \
            hipLaunchKernelGGL((conv3x3_v3<S, TWv, THv, 0>),                   \
                               dim3(nTX_ * nTY_, nCog_, Bn), dim3(256), 0,     \
                               stream, inp, wTb, Bp, Ap, dst, Ci_, Ci_,        \
                               Hi_, Wi_, Co_, Ho_, Wo_, nTX_, nCog_);          \
        } else {                                                               \
            hipLaunchKernelGGL((conv3x3_v3<S, TWv, THv, 1>),                   \
                               dim3(nTX_ * nTY_, nCog_ * (CSPLv), Bn),         \
                               dim3(256), 0, stream, inp, wTb,                 \
                               (const float*)nullptr, (const float*)nullptr,   \
                               p1, Ci_, (Ci_) / (CSPLv), Hi_, Wi_, Co_,        \
                               Ho_, Wo_, nTX_, nCog_);                         \
            const int N4_ = Bn * (Co_) * Ho_ * Wo_ / 4;                        \
            hipLaunchKernelGGL(reduce_prelu_kernel, dim3(CDIV(N4_, 256)),      \
                               dim3(256), 0, stream, p1, Bp, Ap, dst, CSPLv,   \
                               N4_, Co_, Ho_ * Wo_);                           \
        }                                                                      \
    } while (0)

#define SPLAT(TSv, Kv, NCHv, HCAPv, featp, flp, op, C_, H_, W_, thr)           \
    do {                                                                       \
        hipMemsetAsync(cnt, 0, (size_t)Bn * (H_) * (W_) * sizeof(float),       \
                       stream);                                                \
        hipLaunchKernelGGL(splat_outlier_kernel,                               \
                           dim3(CDIV(Bn * (H_) * (W_), 256)), dim3(256), 0,    \
                           stream, featp, flp, op, cnt, Bn, C_, H_, W_, thr);  \
        hipLaunchKernelGGL((splat_gather2_kernel<TSv, Kv, NCHv, HCAPv>),       \
                           dim3(((W_) / (TSv)) * ((H_) / (TSv)),               \
                                (C_) / (NCHv), Bn),                            \
                           dim3(256), 0, stream, featp, flp, cnt, op,          \
                           C_, H_, W_, (W_) / (TSv));                          \
    } while (0)

    // ---- level 1 convs (p1 used as 16M temp for conv1a output)
    DO_CONV(2, 32, 16, 1, img, P[0][0], P[0][1], P[0][2], p1, 3, 512, 512, 16);
    DO_CONV(1, 32, 32, 1, p1,  P[0][3], P[0][4], P[0][5], W0, 16, 256, 256, 16);
    halve(flow, fl1, 512, 512);

    // ---- level 2
    DO_CONV(2, 32, 16, 1, W0, P[1][0], P[1][1], P[1][2], A,  16, 256, 256, 32);
    DO_CONV(1, 32, 32, 2, A,  P[1][3], P[1][4], P[1][5], Bf, 32, 128, 128, 32);
    halve(fl1, fl2, 256, 256);
    SPLAT(32, 3, 16, 32, Bf, fl2, p2, 32, 128, 128, 2.f);

    // ---- level 3
    DO_CONV(2, 32, 16, 2, Bf, P[2][0], P[2][1], P[2][2], A,  32, 128, 128, 64);
    DO_CONV(1, 32, 32, 4, A,  P[2][3], P[2][4], P[2][5], Bf, 64, 64, 64, 64);
    halve(fl2, fl3, 128, 128);
    SPLAT(16, 2, 16, 16, Bf, fl3, p3, 64, 64, 64, 1.f);

    // ---- level 4
    DO_CONV(2, 32, 16, 4, Bf, P[3][0], P[3][1], P[3][2], A,  64, 64, 64, 128);
    DO_CONV(1, 32, 32, 8, A,  P[3][3], P[3][4], P[3][5], Bf, 128, 32, 32, 128);
    halve(fl3, fl4, 64, 64);
    SPLAT(16, 2, 16, 16, Bf, fl4, p4, 128, 32, 32, 1.f);

    // ---- level 1 splat last: clear partial scratch from p1, then splat
    hipMemsetAsync(p1, 0, (size_t)16777216 * sizeof(float), stream);
    SPLAT(32, 4, 16, 32, W0, fl1, p1, 16, 256, 256, 3.f);

#undef DO_CONV
#undef SPLAT
}